// Round 15
// baseline (617.899 us; speedup 1.0000x reference)
//
#include <hip/hip_runtime.h>

typedef short bf16x8 __attribute__((ext_vector_type(8)));
typedef float f32x4 __attribute__((ext_vector_type(4)));

#define HDIM 128
#define BM 64    // edges per tile
#define PE 256   // e_in pitch (elems) = 512B: multiple of 128B -> pure-XOR banking
#define PT 128   // mid pitch (elems) = 256B: multiple of 128B

// XOR bank swizzle (T2/G4): permutes 16B chunks within each 128B window.
// Applied identically on write and read -> bijective -> bit-exact.
__device__ __forceinline__ int SW(int row, int col_elem) {
  return col_elem ^ ((row & 7) << 3);
}

__device__ __forceinline__ unsigned short f2bf(float f) {
  union { float f; unsigned int u; } v; v.f = f;
  unsigned int r = v.u + 0x7fffu + ((v.u >> 16) & 1u);
  return (unsigned short)(r >> 16);
}
__device__ __forceinline__ float bf2f(unsigned short u) {
  union { unsigned int u; float f; } v; v.u = ((unsigned int)u) << 16; return v.f;
}
// silu via hardware rcp (no precise-division expansion); bf16-accurate
__device__ __forceinline__ float siluf(float x) {
  return x * __builtin_amdgcn_rcpf(1.f + __expf(-x));
}
__device__ __forceinline__ f32x4 mfma16(bf16x8 a, bf16x8 b, f32x4 c) {
  return __builtin_amdgcn_mfma_f32_16x16x32_bf16(a, b, c, 0, 0, 0);
}

// ---------------- prep ----------------
__global__ void k_cast_h(const float* __restrict__ h, unsigned short* __restrict__ hbf, int n8) {
  int i = blockIdx.x * blockDim.x + threadIdx.x;
  if (i >= n8) return;
  const float4* s = (const float4*)(h + (size_t)i * 8);
  float4 a = s[0], b = s[1];
  union { unsigned short us[8]; uint4 q; } p;
  p.us[0] = f2bf(a.x); p.us[1] = f2bf(a.y); p.us[2] = f2bf(a.z); p.us[3] = f2bf(a.w);
  p.us[4] = f2bf(b.x); p.us[5] = f2bf(b.y); p.us[6] = f2bf(b.z); p.us[7] = f2bf(b.w);
  ((uint4*)hbf)[i] = p.q;
}

// all 5 weight transposes in one launch. Wt[n*K+k] = bf16(W[k*Nn+n])
__global__ void k_prep_w(const float* __restrict__ We1, const float* __restrict__ We2,
                         const float* __restrict__ Wc1, const float* __restrict__ Wn1,
                         const float* __restrict__ Wn2,
                         unsigned short* __restrict__ We1t, unsigned short* __restrict__ We2t,
                         unsigned short* __restrict__ Wc1t, unsigned short* __restrict__ Wn1t,
                         unsigned short* __restrict__ Wn2t) {
  int i = blockIdx.x * 256 + threadIdx.x;
  const int S1 = 256 * 128, S2 = 128 * 128;
  const float* W; unsigned short* Wt; int K, base;
  if (i < S1)                     { W = We1; Wt = We1t; K = 256; base = 0; }
  else if (i < S1 + S2)           { W = We2; Wt = We2t; K = 128; base = S1; }
  else if (i < S1 + 2 * S2)       { W = Wc1; Wt = Wc1t; K = 128; base = S1 + S2; }
  else if (i < 2 * S1 + 2 * S2)   { W = Wn1; Wt = Wn1t; K = 256; base = S1 + 2 * S2; }
  else if (i < 2 * S1 + 3 * S2)   { W = Wn2; Wt = Wn2t; K = 128; base = 2 * S1 + 2 * S2; }
  else return;
  int j = i - base;
  int k = j >> 7, n = j & 127;          // Nn == 128 everywhere
  Wt[n * K + k] = f2bf(W[j]);
}

// ---------------- counting sort by row ----------------
__global__ void k_hist(const int* __restrict__ ei, int* __restrict__ deg, int E) {
  int e = blockIdx.x * blockDim.x + threadIdx.x;
  if (e < E) atomicAdd(&deg[ei[e]], 1);
}

__global__ void k_scan1(const int* __restrict__ deg, int* __restrict__ partial, int N) {
  int i = blockIdx.x * 256 + threadIdx.x;
  int v = (i < N) ? deg[i] : 0;
#pragma unroll
  for (int m = 1; m < 64; m <<= 1) v += __shfl_xor(v, m);
  __shared__ int ws[4];
  if ((threadIdx.x & 63) == 0) ws[threadIdx.x >> 6] = v;
  __syncthreads();
  if (threadIdx.x == 0) partial[blockIdx.x] = ws[0] + ws[1] + ws[2] + ws[3];
}

__global__ void k_scan2(int* __restrict__ partial, int nb) {
  __shared__ int arr[256];
  int t = threadIdx.x;
  int self = (t < nb) ? partial[t] : 0;
  arr[t] = self;
  __syncthreads();
  for (int o = 1; o < 256; o <<= 1) {
    int u = (t >= o) ? arr[t - o] : 0;
    __syncthreads();
    arr[t] += u;
    __syncthreads();
  }
  if (t < nb) partial[t] = arr[t] - self;   // exclusive
}

__global__ void k_scan3(const int* __restrict__ deg, const int* __restrict__ partial,
                        int* __restrict__ row_start, int* __restrict__ cursor, int N, int E) {
  __shared__ int arr[256];
  int b = blockIdx.x, t = threadIdx.x, i = b * 256 + t;
  int v = (i < N) ? deg[i] : 0;
  arr[t] = v;
  __syncthreads();
  for (int o = 1; o < 256; o <<= 1) {
    int u = (t >= o) ? arr[t - o] : 0;
    __syncthreads();
    arr[t] += u;
    __syncthreads();
  }
  if (i < N) {
    int ex = partial[b] + arr[t] - v;
    row_start[i] = ex; cursor[i] = ex;
  }
  if (b == 0 && t == 0) row_start[N] = E;
}

__global__ void k_scatter(const int* __restrict__ ei, int* __restrict__ cursor,
                          int* __restrict__ srow, int* __restrict__ scol, int E) {
  int e = blockIdx.x * blockDim.x + threadIdx.x;
  if (e < E) {
    int r = ei[e];
    int pos = atomicAdd(&cursor[r], 1);
    srow[pos] = r;
    scol[pos] = ei[E + e];
  }
}

// ---------------- edge kernel: sorted edges, BM=64, 8 waves x 16 cols,
//                  XCD-chunked, zero atomics, streams ef + trans.
//                  XOR-swizzled LDS (pow2 pitches) to kill bank conflicts.
// (512,4): 2 blocks/CU — the ONLY safe shape ((512,6) spills weights). -------
__global__ __launch_bounds__(512, 4)
void k_edge(const float* __restrict__ coord,
            const int* __restrict__ srow,
            const int* __restrict__ scol,
            const unsigned short* __restrict__ hbf,
            const unsigned short* __restrict__ We1t,
            const unsigned short* __restrict__ We2t,
            const unsigned short* __restrict__ Wc1t,
            const float* __restrict__ We1,   // [257][128], row 256 = radial row
            const float* __restrict__ be1,
            const float* __restrict__ be2,
            const float* __restrict__ bc1,
            const float* __restrict__ Wc2,   // [128]
            unsigned short* __restrict__ ef,   // [E][128] bf16 out
            float* __restrict__ trans,         // [E][3] f32 out
            int E)
{
  __shared__ unsigned short e_in[BM * PE];   // also hosts ef_t (disjoint in time)
  __shared__ unsigned short m_t[BM * PT];
  __shared__ float cd_lds[BM][3];
  __shared__ float rad_lds[BM];
  __shared__ float w_part[8][BM];
  unsigned short* ef_t = e_in;   // layer-2 output (PT pitch); e_in reads end before B2

  const int tid = threadIdx.x;
  const int lane = tid & 63;
  const int wv = tid >> 6;      // wave 0..7, owns cols [wv*16, wv*16+16)
  const int l15 = lane & 15;
  const int lg = lane >> 4;     // 0..3
  const int n_own = wv * 16 + l15;

  // ---- weight B-fragments in registers (per wave: its 16 cols) ----
  bf16x8 fW1[8], fW2[4], fW3[4];
#pragma unroll
  for (int kt = 0; kt < 8; ++kt)
    fW1[kt] = *(const bf16x8*)&We1t[n_own * 256 + kt * 32 + lg * 8];
#pragma unroll
  for (int kt = 0; kt < 4; ++kt) {
    fW2[kt] = *(const bf16x8*)&We2t[n_own * 128 + kt * 32 + lg * 8];
    fW3[kt] = *(const bf16x8*)&Wc1t[n_own * 128 + kt * 32 + lg * 8];
  }
  const float bias1 = be1[n_own], bias2 = be2[n_own], bias3 = bc1[n_own];
  const float wc2v = Wc2[n_own];
  const float w256 = We1[256 * 128 + n_own];

  // ---- XCD-chunked contiguous tile range ----
  const int ntiles = (E + BM - 1) / BM;
  const int nblk = gridDim.x;                 // multiple of 8
  const int vbid = (blockIdx.x & 7) * (nblk >> 3) + (blockIdx.x >> 3);
  const int tpb = (ntiles + nblk - 1) / nblk;
  int lo = vbid * tpb, hi = lo + tpb; if (hi > ntiles) hi = ntiles;

  const int gslot = tid >> 2, gpart = tid & 3;   // slot 0..127, part 0..3 (64B each)
  const int gm = gslot >> 1, ghalf = gslot & 1;  // edge-in-tile, h[row]/h[col] half
  const int cm = tid >> 3, cpart = tid & 7;      // ef copy: row 0..63, 32B part 0..7

  for (int t = lo; t < hi; ++t) {
    const int e0 = t * BM;

    // ---- stage: geometry + gather h rows into swizzled e_in ----
    if (tid < BM) {   // wave 0
      int e = e0 + tid;
      float dx = 0.f, dy = 0.f, dz = 0.f;
      if (e < E) {
        int r = srow[e], c = scol[e];
        dx = coord[r * 3 + 0] - coord[c * 3 + 0];
        dy = coord[r * 3 + 1] - coord[c * 3 + 1];
        dz = coord[r * 3 + 2] - coord[c * 3 + 2];
      }
      cd_lds[tid][0] = dx; cd_lds[tid][1] = dy; cd_lds[tid][2] = dz;
      rad_lds[tid] = dx * dx + dy * dy + dz * dz;
    }
    {
      // 512 threads x 64B = 32KB = 64 edges x 2 nodes x 128 shorts
      int e = e0 + gm;
      int node = 0;
      if (e < E) node = ghalf ? scol[e] : srow[e];
      const uint4* src = (const uint4*)&hbf[(size_t)node * HDIM + gpart * 32];
      uint4 a = src[0], b = src[1], c = src[2], d = src[3];
      int cb = ghalf * HDIM + gpart * 32;   // elem col base of the 4 chunks
      *(uint4*)&e_in[gm * PE + SW(gm, cb +  0)] = a;
      *(uint4*)&e_in[gm * PE + SW(gm, cb +  8)] = b;
      *(uint4*)&e_in[gm * PE + SW(gm, cb + 16)] = c;
      *(uint4*)&e_in[gm * PE + SW(gm, cb + 24)] = d;
    }
    __syncthreads();   // B1

    // ---- layer 1: [64 x 256] @ We1[256 x 128] ----
    f32x4 acc[4];
#pragma unroll
    for (int mt = 0; mt < 4; ++mt) acc[mt] = (f32x4){0.f, 0.f, 0.f, 0.f};
#pragma unroll
    for (int kt = 0; kt < 8; ++kt) {
#pragma unroll
      for (int mt = 0; mt < 4; ++mt) {
        int row = mt * 16 + l15;
        bf16x8 a = *(const bf16x8*)&e_in[row * PE + SW(row, kt * 32 + lg * 8)];
        acc[mt] = mfma16(a, fW1[kt], acc[mt]);
      }
    }
#pragma unroll
    for (int mt = 0; mt < 4; ++mt)
#pragma unroll
      for (int r = 0; r < 4; ++r) {
        int m = mt * 16 + lg * 4 + r;
        float x = acc[mt][r] + bias1 + rad_lds[m] * w256;
        m_t[m * PT + SW(m, n_own)] = f2bf(siluf(x));
      }
    __syncthreads();   // B2 (all e_in reads done; ef_t may now overwrite it)

    // ---- layer 2: m @ We2 -> edge_feat ----
#pragma unroll
    for (int mt = 0; mt < 4; ++mt) acc[mt] = (f32x4){0.f, 0.f, 0.f, 0.f};
#pragma unroll
    for (int kt = 0; kt < 4; ++kt) {
#pragma unroll
      for (int mt = 0; mt < 4; ++mt) {
        int row = mt * 16 + l15;
        bf16x8 a = *(const bf16x8*)&m_t[row * PT + SW(row, kt * 32 + lg * 8)];
        acc[mt] = mfma16(a, fW2[kt], acc[mt]);
      }
    }
#pragma unroll
    for (int mt = 0; mt < 4; ++mt)
#pragma unroll
      for (int r = 0; r < 4; ++r) {
        int m = mt * 16 + lg * 4 + r;
        ef_t[m * PT + SW(m, n_own)] = f2bf(siluf(acc[mt][r] + bias2));
      }
    __syncthreads();   // B3

    // ---- stream ef tile to global (de-swizzle on read; coalesced stores) ----
    if (e0 + cm < E) {
      uint4 a = *(const uint4*)&ef_t[cm * PT + SW(cm, cpart * 16 + 0)];
      uint4 b = *(const uint4*)&ef_t[cm * PT + SW(cm, cpart * 16 + 8)];
      uint4* dst = (uint4*)&ef[(size_t)(e0 + cm) * HDIM + cpart * 16];
      dst[0] = a; dst[1] = b;
    }

    // ---- layer 3: edge_feat @ Wc1 -> silu -> dot Wc2 ----
#pragma unroll
    for (int mt = 0; mt < 4; ++mt) acc[mt] = (f32x4){0.f, 0.f, 0.f, 0.f};
#pragma unroll
    for (int kt = 0; kt < 4; ++kt) {
#pragma unroll
      for (int mt = 0; mt < 4; ++mt) {
        int row = mt * 16 + l15;
        bf16x8 a = *(const bf16x8*)&ef_t[row * PT + SW(row, kt * 32 + lg * 8)];
        acc[mt] = mfma16(a, fW3[kt], acc[mt]);
      }
    }
    float vsum[4][4];
#pragma unroll
    for (int mt = 0; mt < 4; ++mt)
#pragma unroll
      for (int r = 0; r < 4; ++r)
        vsum[mt][r] = siluf(acc[mt][r] + bias3) * wc2v;
#pragma unroll
    for (int mask = 1; mask < 16; mask <<= 1)
#pragma unroll
      for (int mt = 0; mt < 4; ++mt)
#pragma unroll
        for (int r = 0; r < 4; ++r)
          vsum[mt][r] += __shfl_xor(vsum[mt][r], mask);
    if (l15 == 0) {
#pragma unroll
      for (int mt = 0; mt < 4; ++mt)
#pragma unroll
        for (int r = 0; r < 4; ++r)
          w_part[wv][mt * 16 + lg * 4 + r] = vsum[mt][r];
    }
    __syncthreads();   // B4 (w_part complete)

    // ---- trans: per-edge plain store (no atomics; summed later by CSR) ----
    if (tid < 3 * BM) {
      int m = tid / 3, axis = tid - m * 3;
      int e = e0 + m;
      if (e < E) {
        float w = 0.f;
#pragma unroll
        for (int q8 = 0; q8 < 8; ++q8) w += w_part[q8][m];
        trans[(size_t)e * 3 + axis] = cd_lds[m][axis] * w;
      }
    }
    __syncthreads();   // B5 (protect LDS for next tile)
  }
}

// ---------------- node kernel: CSR agg (vectorized) + node MLP + coord ----
#define NBM 32
__global__ __launch_bounds__(256, 4)
void k_node(const float* __restrict__ h,
            const unsigned short* __restrict__ hbf,
            const unsigned short* __restrict__ ef,   // [E][128]
            const float* __restrict__ trans,         // [E][3]
            const float* __restrict__ coord,
            const int* __restrict__ row_start,       // [N+1]
            const unsigned short* __restrict__ Wn1t,
            const unsigned short* __restrict__ Wn2t,
            const float* __restrict__ bn1,
            const float* __restrict__ bn2,
            float* __restrict__ hout,
            float* __restrict__ cout,
            int N)
{
  __shared__ unsigned short a_in[NBM * PE];
  __shared__ unsigned short t1[NBM * PT];
  const int tid = threadIdx.x, lane = tid & 63, wv = tid >> 6;
  const int l15 = lane & 15, lg = lane >> 4;

  bf16x8 fW1[2][8], fW2[2][4];
  float b1v[2], b2v[2];
#pragma unroll
  for (int nt = 0; nt < 2; ++nt) {
    int n = wv * 32 + nt * 16 + l15;
#pragma unroll
    for (int kt = 0; kt < 8; ++kt)
      fW1[nt][kt] = *(const bf16x8*)&Wn1t[n * 256 + kt * 32 + lg * 8];
#pragma unroll
    for (int kt = 0; kt < 4; ++kt)
      fW2[nt][kt] = *(const bf16x8*)&Wn2t[n * 128 + kt * 32 + lg * 8];
    b1v[nt] = bn1[n]; b2v[nt] = bn2[n];
  }

  const int ntiles = (N + NBM - 1) / NBM;
  for (int t = blockIdx.x; t < ntiles; t += gridDim.x) {
    const int base = t * NBM;
    // ---- stage h half: 256 threads x 32B = 8KB ----
    {
      int m = tid >> 3, part = tid & 7;
      int node = base + m; if (node >= N) node = N - 1;
      const uint4* src = (const uint4*)&hbf[(size_t)node * HDIM + part * 16];
      uint4 a = src[0], b = src[1];
      *(uint4*)&a_in[m * PE + SW(m, part * 16 + 0)] = a;
      *(uint4*)&a_in[m * PE + SW(m, part * 16 + 8)] = b;
    }
    // ---- agg half: 512 units = (m:32) x (cg:16, 8 cols); 2 units/thread ----
    {
      int unit = tid;
#pragma unroll
      for (int u = 0; u < 2; ++u, unit += 256) {
        int m = unit >> 4, cg = unit & 15;
        int node = base + m;
        float s[8] = {0.f, 0.f, 0.f, 0.f, 0.f, 0.f, 0.f, 0.f};
        if (node < N) {
          int er0 = row_start[node], er1 = row_start[node + 1];
#pragma unroll 4
          for (int e = er0; e < er1; ++e) {
            bf16x8 v = *(const bf16x8*)&ef[(size_t)e * HDIM + cg * 8];
#pragma unroll
            for (int j = 0; j < 8; ++j)
              s[j] += bf2f((unsigned short)v[j]);
          }
        }
        union { unsigned short us[8]; uint4 q; } p;
#pragma unroll
        for (int j = 0; j < 8; ++j) p.us[j] = f2bf(s[j]);
        *(uint4*)&a_in[m * PE + SW(m, HDIM + cg * 8)] = p.q;
      }
    }
    // ---- coord epilogue for this tile's nodes (independent of MLP) ----
    if (tid < 3 * NBM) {
      int m = tid / 3, axis = tid - m * 3;
      int node = base + m;
      if (node < N) {
        int er0 = row_start[node], er1 = row_start[node + 1];
        float s = 0.f;
        for (int e = er0; e < er1; ++e) s += trans[(size_t)e * 3 + axis];
        float c = (float)(er1 - er0); if (c < 1.f) c = 1.f;
        cout[(size_t)node * 3 + axis] = coord[(size_t)node * 3 + axis] + s / c;
      }
    }
    __syncthreads();

    f32x4 acc[2][2];
#pragma unroll
    for (int mt = 0; mt < 2; ++mt)
#pragma unroll
      for (int nt = 0; nt < 2; ++nt)
        acc[mt][nt] = (f32x4){0.f, 0.f, 0.f, 0.f};
#pragma unroll
    for (int kt = 0; kt < 8; ++kt) {
      int r0 = l15, r1 = 16 + l15;
      bf16x8 a0 = *(const bf16x8*)&a_in[r0 * PE + SW(r0, kt * 32 + lg * 8)];
      bf16x8 a1 = *(const bf16x8*)&a_in[r1 * PE + SW(r1, kt * 32 + lg * 8)];
#pragma unroll
      for (int nt = 0; nt < 2; ++nt) {
        acc[0][nt] = mfma16(a0, fW1[nt][kt], acc[0][nt]);
        acc[1][nt] = mfma16(a1, fW1[nt][kt], acc[1][nt]);
      }
    }
#pragma unroll
    for (int mt = 0; mt < 2; ++mt)
#pragma unroll
      for (int nt = 0; nt < 2; ++nt) {
        int n = wv * 32 + nt * 16 + l15;
#pragma unroll
        for (int r = 0; r < 4; ++r) {
          int m = mt * 16 + lg * 4 + r;
          t1[m * PT + SW(m, n)] = f2bf(siluf(acc[mt][nt][r] + b1v[nt]));
        }
      }
    __syncthreads();

    f32x4 acc2[2][2];
#pragma unroll
    for (int mt = 0; mt < 2; ++mt)
#pragma unroll
      for (int nt = 0; nt < 2; ++nt)
        acc2[mt][nt] = (f32x4){0.f, 0.f, 0.f, 0.f};
#pragma unroll
    for (int kt = 0; kt < 4; ++kt) {
      int r0 = l15, r1 = 16 + l15;
      bf16x8 a0 = *(const bf16x8*)&t1[r0 * PT + SW(r0, kt * 32 + lg * 8)];
      bf16x8 a1 = *(const bf16x8*)&t1[r1 * PT + SW(r1, kt * 32 + lg * 8)];
#pragma unroll
      for (int nt = 0; nt < 2; ++nt) {
        acc2[0][nt] = mfma16(a0, fW2[nt][kt], acc2[0][nt]);
        acc2[1][nt] = mfma16(a1, fW2[nt][kt], acc2[1][nt]);
      }
    }
#pragma unroll
    for (int mt = 0; mt < 2; ++mt)
#pragma unroll
      for (int nt = 0; nt < 2; ++nt) {
        int n = wv * 32 + nt * 16 + l15;
#pragma unroll
        for (int r = 0; r < 4; ++r) {
          int node = base + mt * 16 + lg * 4 + r;
          if (node < N)
            hout[(size_t)node * HDIM + n] = h[(size_t)node * HDIM + n] + acc2[mt][nt][r] + b2v[nt];
        }
      }
    __syncthreads();
  }
}

extern "C" void kernel_launch(void* const* d_in, const int* in_sizes, int n_in,
                              void* d_out, int out_size, void* d_ws, size_t ws_size,
                              hipStream_t stream) {
  const float* h     = (const float*)d_in[0];
  const float* coord = (const float*)d_in[1];
  const int*   ei    = (const int*)d_in[2];
  const float* We1   = (const float*)d_in[3];
  const float* be1   = (const float*)d_in[4];
  const float* We2   = (const float*)d_in[5];
  const float* be2   = (const float*)d_in[6];
  const float* Wn1   = (const float*)d_in[7];
  const float* bn1   = (const float*)d_in[8];
  const float* Wn2   = (const float*)d_in[9];
  const float* bn2   = (const float*)d_in[10];
  const float* Wc1   = (const float*)d_in[11];
  const float* bc1   = (const float*)d_in[12];
  const float* Wc2   = (const float*)d_in[13];

  const int N = in_sizes[0] / HDIM;
  const int E = in_sizes[2] / 2;

  char* ws = (char*)d_ws;
  size_t off = 0;
  auto alloc = [&](size_t b) { void* p = ws + off; off = (off + b + 255) & ~(size_t)255; return p; };
  unsigned short* hbf  = (unsigned short*)alloc((size_t)N * HDIM * 2);
  unsigned short* We1t = (unsigned short*)alloc(256 * 128 * 2);
  unsigned short* We2t = (unsigned short*)alloc(128 * 128 * 2);
  unsigned short* Wc1t = (unsigned short*)alloc(128 * 128 * 2);
  unsigned short* Wn1t = (unsigned short*)alloc(256 * 128 * 2);
  unsigned short* Wn2t = (unsigned short*)alloc(128 * 128 * 2);
  int* deg       = (int*)alloc((size_t)N * 4);
  int* cursor    = (int*)alloc((size_t)N * 4);
  int* row_start = (int*)alloc(((size_t)N + 1) * 4);
  int* partial   = (int*)alloc(256 * 4);
  int* srow      = (int*)alloc((size_t)E * 4);
  int* scol      = (int*)alloc((size_t)E * 4);
  unsigned short* ef = (unsigned short*)alloc((size_t)E * HDIM * 2);  // 205 MB
  float* trans   = (float*)alloc((size_t)E * 3 * 4);                  // 9.6 MB

  hipMemsetAsync(deg, 0, (size_t)N * 4, stream);

  int n8 = N * HDIM / 8;
  k_cast_h<<<(n8 + 255) / 256, 256, 0, stream>>>(h, hbf, n8);
  int wtot = 2 * 256 * 128 + 3 * 128 * 128;
  k_prep_w<<<(wtot + 255) / 256, 256, 0, stream>>>(We1, We2, Wc1, Wn1, Wn2,
                                                   We1t, We2t, Wc1t, Wn1t, Wn2t);

  // counting sort by row (parallel scan)
  int nb = (N + 255) / 256;   // <= 256
  k_hist<<<(E + 255) / 256, 256, 0, stream>>>(ei, deg, E);
  k_scan1<<<nb, 256, 0, stream>>>(deg, partial, N);
  k_scan2<<<1, 256, 0, stream>>>(partial, nb);
  k_scan3<<<nb, 256, 0, stream>>>(deg, partial, row_start, cursor, N, E);
  k_scatter<<<(E + 255) / 256, 256, 0, stream>>>(ei, cursor, srow, scol, E);

  k_edge<<<512, 512, 0, stream>>>(coord, srow, scol, hbf, We1t, We2t, Wc1t, We1,
                                  be1, be2, bc1, Wc2, ef, trans, E);

  float* hout = (float*)d_out;
  float* cout = hout + (size_t)N * HDIM;
  int node_tiles = (N + NBM - 1) / NBM;
  k_node<<<node_tiles, 256, 0, stream>>>(h, hbf, ef, trans, coord, row_start,
                                         Wn1t, Wn2t, bn1, bn2, hout, cout, N);
}

// Round 16
// 478.452 us; speedup vs baseline: 1.2915x; 1.2915x over previous
//
#include <hip/hip_runtime.h>

typedef short bf16x8 __attribute__((ext_vector_type(8)));
typedef float f32x4 __attribute__((ext_vector_type(4)));

#define HDIM 128
#define BM 64    // edges per tile
#define PE 264   // e_in tile pitch (elems): 528B
#define PT 136   // mid tile pitch (elems): 272B

__device__ __forceinline__ unsigned short f2bf(float f) {
  union { float f; unsigned int u; } v; v.f = f;
  unsigned int r = v.u + 0x7fffu + ((v.u >> 16) & 1u);
  return (unsigned short)(r >> 16);
}
__device__ __forceinline__ float bf2f(unsigned short u) {
  union { unsigned int u; float f; } v; v.u = ((unsigned int)u) << 16; return v.f;
}
// silu via hardware rcp (no precise-division expansion); bf16-accurate
__device__ __forceinline__ float siluf(float x) {
  return x * __builtin_amdgcn_rcpf(1.f + __expf(-x));
}
__device__ __forceinline__ f32x4 mfma16(bf16x8 a, bf16x8 b, f32x4 c) {
  return __builtin_amdgcn_mfma_f32_16x16x32_bf16(a, b, c, 0, 0, 0);
}

// ---------------- prep ----------------
__global__ void k_cast_h(const float* __restrict__ h, unsigned short* __restrict__ hbf, int n8) {
  int i = blockIdx.x * blockDim.x + threadIdx.x;
  if (i >= n8) return;
  const float4* s = (const float4*)(h + (size_t)i * 8);
  float4 a = s[0], b = s[1];
  union { unsigned short us[8]; uint4 q; } p;
  p.us[0] = f2bf(a.x); p.us[1] = f2bf(a.y); p.us[2] = f2bf(a.z); p.us[3] = f2bf(a.w);
  p.us[4] = f2bf(b.x); p.us[5] = f2bf(b.y); p.us[6] = f2bf(b.z); p.us[7] = f2bf(b.w);
  ((uint4*)hbf)[i] = p.q;
}

// Wt[n*K + k] = bf16(W[k*Nn + n])
__global__ void k_transpose(const float* __restrict__ W, unsigned short* __restrict__ Wt, int K, int Nn) {
  int i = blockIdx.x * blockDim.x + threadIdx.x;
  if (i >= K * Nn) return;
  int k = i / Nn, n = i - k * Nn;
  Wt[n * K + k] = f2bf(W[i]);
}

// ---------------- counting sort by row ----------------
__global__ void k_hist(const int* __restrict__ ei, int* __restrict__ deg, int E) {
  int e = blockIdx.x * blockDim.x + threadIdx.x;
  if (e < E) atomicAdd(&deg[ei[e]], 1);
}

__global__ void k_scan1(const int* __restrict__ deg, int* __restrict__ partial, int N) {
  int i = blockIdx.x * 256 + threadIdx.x;
  int v = (i < N) ? deg[i] : 0;
#pragma unroll
  for (int m = 1; m < 64; m <<= 1) v += __shfl_xor(v, m);
  __shared__ int ws[4];
  if ((threadIdx.x & 63) == 0) ws[threadIdx.x >> 6] = v;
  __syncthreads();
  if (threadIdx.x == 0) partial[blockIdx.x] = ws[0] + ws[1] + ws[2] + ws[3];
}

__global__ void k_scan2(int* __restrict__ partial, int nb) {
  __shared__ int arr[256];
  int t = threadIdx.x;
  int self = (t < nb) ? partial[t] : 0;
  arr[t] = self;
  __syncthreads();
  for (int o = 1; o < 256; o <<= 1) {
    int u = (t >= o) ? arr[t - o] : 0;
    __syncthreads();
    arr[t] += u;
    __syncthreads();
  }
  if (t < nb) partial[t] = arr[t] - self;   // exclusive
}

__global__ void k_scan3(const int* __restrict__ deg, const int* __restrict__ partial,
                        int* __restrict__ row_start, int* __restrict__ cursor, int N, int E) {
  __shared__ int arr[256];
  int b = blockIdx.x, t = threadIdx.x, i = b * 256 + t;
  int v = (i < N) ? deg[i] : 0;
  arr[t] = v;
  __syncthreads();
  for (int o = 1; o < 256; o <<= 1) {
    int u = (t >= o) ? arr[t - o] : 0;
    __syncthreads();
    arr[t] += u;
    __syncthreads();
  }
  if (i < N) {
    int ex = partial[b] + arr[t] - v;
    row_start[i] = ex; cursor[i] = ex;
  }
  if (b == 0 && t == 0) row_start[N] = E;
}

__global__ void k_scatter(const int* __restrict__ ei, int* __restrict__ cursor,
                          int* __restrict__ srow, int* __restrict__ scol, int E) {
  int e = blockIdx.x * blockDim.x + threadIdx.x;
  if (e < E) {
    int r = ei[e];
    int pos = atomicAdd(&cursor[r], 1);
    srow[pos] = r;
    scol[pos] = ei[E + e];
  }
}

// ---------------- edge kernel: sorted edges, BM=64, 8 waves x 16 cols,
//                  XCD-chunked, zero atomics, streams ef + trans ----------------
__global__ __launch_bounds__(512, 4)
void k_edge(const float* __restrict__ coord,
            const int* __restrict__ srow,
            const int* __restrict__ scol,
            const unsigned short* __restrict__ hbf,
            const unsigned short* __restrict__ We1t,
            const unsigned short* __restrict__ We2t,
            const unsigned short* __restrict__ Wc1t,
            const float* __restrict__ We1,   // [257][128], row 256 = radial row
            const float* __restrict__ be1,
            const float* __restrict__ be2,
            const float* __restrict__ bc1,
            const float* __restrict__ Wc2,   // [128]
            unsigned short* __restrict__ ef,   // [E][128] bf16 out
            float* __restrict__ trans,         // [E][3] f32 out
            int E)
{
  __shared__ unsigned short e_in[BM * PE];   // also hosts ef_t (disjoint in time)
  __shared__ unsigned short m_t[BM * PT];
  __shared__ float cd_lds[BM][3];
  __shared__ float rad_lds[BM];
  __shared__ float w_part[8][BM];
  __shared__ int rows_lds[BM];
  unsigned short* ef_t = e_in;   // layer-2 output; e_in reads end before B2

  const int tid = threadIdx.x;
  const int lane = tid & 63;
  const int wv = tid >> 6;      // wave 0..7, owns cols [wv*16, wv*16+16)
  const int l15 = lane & 15;
  const int lg = lane >> 4;     // 0..3
  const int n_own = wv * 16 + l15;

  // ---- weight B-fragments in registers (per wave: its 16 cols) ----
  bf16x8 fW1[8], fW2[4], fW3[4];
#pragma unroll
  for (int kt = 0; kt < 8; ++kt)
    fW1[kt] = *(const bf16x8*)&We1t[n_own * 256 + kt * 32 + lg * 8];
#pragma unroll
  for (int kt = 0; kt < 4; ++kt) {
    fW2[kt] = *(const bf16x8*)&We2t[n_own * 128 + kt * 32 + lg * 8];
    fW3[kt] = *(const bf16x8*)&Wc1t[n_own * 128 + kt * 32 + lg * 8];
  }
  const float bias1 = be1[n_own], bias2 = be2[n_own], bias3 = bc1[n_own];
  const float wc2v = Wc2[n_own];
  const float w256 = We1[256 * 128 + n_own];

  // ---- XCD-chunked contiguous tile range ----
  const int ntiles = (E + BM - 1) / BM;
  const int nblk = gridDim.x;                 // multiple of 8
  const int vbid = (blockIdx.x & 7) * (nblk >> 3) + (blockIdx.x >> 3);
  const int tpb = (ntiles + nblk - 1) / nblk;
  int lo = vbid * tpb, hi = lo + tpb; if (hi > ntiles) hi = ntiles;

  const int gslot = tid >> 2, gpart = tid & 3;   // slot 0..127, part 0..3 (64B each)
  const int gm = gslot >> 1, ghalf = gslot & 1;  // edge-in-tile, h[row]/h[col] half
  const int cm = tid >> 3, cpart = tid & 7;      // ef copy: row 0..63, 32B part 0..7

  for (int t = lo; t < hi; ++t) {
    const int e0 = t * BM;

    // ---- stage: indices, coord geometry, gather h rows into e_in ----
    if (tid < BM) {   // wave 0
      int e = e0 + tid;
      if (e < E) {
        int r = srow[e], c = scol[e];
        rows_lds[tid] = r;
        float dx = coord[r * 3 + 0] - coord[c * 3 + 0];
        float dy = coord[r * 3 + 1] - coord[c * 3 + 1];
        float dz = coord[r * 3 + 2] - coord[c * 3 + 2];
        cd_lds[tid][0] = dx; cd_lds[tid][1] = dy; cd_lds[tid][2] = dz;
        rad_lds[tid] = dx * dx + dy * dy + dz * dz;
      } else {
        rows_lds[tid] = -1;
        cd_lds[tid][0] = 0.f; cd_lds[tid][1] = 0.f; cd_lds[tid][2] = 0.f;
        rad_lds[tid] = 0.f;
      }
    }
    {
      // 512 threads x 64B = 32KB = 64 edges x 2 nodes x 128 shorts
      int e = e0 + gm;
      int node = 0;
      if (e < E) node = ghalf ? scol[e] : srow[e];
      const uint4* src = (const uint4*)&hbf[(size_t)node * HDIM + gpart * 32];
      uint4 a = src[0], b = src[1], c = src[2], d = src[3];
      uint4* dst = (uint4*)&e_in[gm * PE + ghalf * HDIM + gpart * 32];
      dst[0] = a; dst[1] = b; dst[2] = c; dst[3] = d;
    }
    __syncthreads();   // B1

    // ---- layer 1: [64 x 256] @ We1[256 x 128] ----
    f32x4 acc[4];
#pragma unroll
    for (int mt = 0; mt < 4; ++mt) acc[mt] = (f32x4){0.f, 0.f, 0.f, 0.f};
#pragma unroll
    for (int kt = 0; kt < 8; ++kt) {
#pragma unroll
      for (int mt = 0; mt < 4; ++mt) {
        bf16x8 a = *(const bf16x8*)&e_in[(mt * 16 + l15) * PE + kt * 32 + lg * 8];
        acc[mt] = mfma16(a, fW1[kt], acc[mt]);
      }
    }
#pragma unroll
    for (int mt = 0; mt < 4; ++mt)
#pragma unroll
      for (int r = 0; r < 4; ++r) {
        int m = mt * 16 + lg * 4 + r;
        float x = acc[mt][r] + bias1 + rad_lds[m] * w256;
        m_t[m * PT + n_own] = f2bf(siluf(x));
      }
    __syncthreads();   // B2 (all e_in reads done; ef_t may now overwrite it)

    // ---- layer 2: m @ We2 -> edge_feat ----
#pragma unroll
    for (int mt = 0; mt < 4; ++mt) acc[mt] = (f32x4){0.f, 0.f, 0.f, 0.f};
#pragma unroll
    for (int kt = 0; kt < 4; ++kt) {
#pragma unroll
      for (int mt = 0; mt < 4; ++mt) {
        bf16x8 a = *(const bf16x8*)&m_t[(mt * 16 + l15) * PT + kt * 32 + lg * 8];
        acc[mt] = mfma16(a, fW2[kt], acc[mt]);
      }
    }
#pragma unroll
    for (int mt = 0; mt < 4; ++mt)
#pragma unroll
      for (int r = 0; r < 4; ++r) {
        int m = mt * 16 + lg * 4 + r;
        ef_t[m * PT + n_own] = f2bf(siluf(acc[mt][r] + bias2));
      }
    __syncthreads();   // B3

    // ---- stream ef tile to global (coalesced, plain stores; overlaps L3) ----
    if (e0 + cm < E) {
      const uint4* src = (const uint4*)&ef_t[cm * PT + cpart * 16];
      uint4 a = src[0], b = src[1];
      uint4* dst = (uint4*)&ef[(size_t)(e0 + cm) * HDIM + cpart * 16];
      dst[0] = a; dst[1] = b;
    }

    // ---- layer 3: edge_feat @ Wc1 -> silu -> dot Wc2 ----
#pragma unroll
    for (int mt = 0; mt < 4; ++mt) acc[mt] = (f32x4){0.f, 0.f, 0.f, 0.f};
#pragma unroll
    for (int kt = 0; kt < 4; ++kt) {
#pragma unroll
      for (int mt = 0; mt < 4; ++mt) {
        bf16x8 a = *(const bf16x8*)&ef_t[(mt * 16 + l15) * PT + kt * 32 + lg * 8];
        acc[mt] = mfma16(a, fW3[kt], acc[mt]);
      }
    }
    float vsum[4][4];
#pragma unroll
    for (int mt = 0; mt < 4; ++mt)
#pragma unroll
      for (int r = 0; r < 4; ++r)
        vsum[mt][r] = siluf(acc[mt][r] + bias3) * wc2v;
#pragma unroll
    for (int mask = 1; mask < 16; mask <<= 1)
#pragma unroll
      for (int mt = 0; mt < 4; ++mt)
#pragma unroll
        for (int r = 0; r < 4; ++r)
          vsum[mt][r] += __shfl_xor(vsum[mt][r], mask);
    if (l15 == 0) {
#pragma unroll
      for (int mt = 0; mt < 4; ++mt)
#pragma unroll
        for (int r = 0; r < 4; ++r)
          w_part[wv][mt * 16 + lg * 4 + r] = vsum[mt][r];
    }
    __syncthreads();   // B4 (w_part complete)

    // ---- trans: per-edge plain store (no atomics; summed later by CSR) ----
    if (tid < 3 * BM) {
      int m = tid / 3, axis = tid - m * 3;
      int e = e0 + m;
      if (e < E) {
        float w = 0.f;
#pragma unroll
        for (int q8 = 0; q8 < 8; ++q8) w += w_part[q8][m];
        trans[(size_t)e * 3 + axis] = cd_lds[m][axis] * w;
      }
    }
    __syncthreads();   // B5 (protect LDS for next tile)
  }
}

// ---------------- node kernel: CSR-contiguous agg (vectorized) + node MLP ----
#define NBM 32
__global__ __launch_bounds__(256, 3)
void k_node(const float* __restrict__ h,
            const unsigned short* __restrict__ hbf,
            const unsigned short* __restrict__ ef,   // [E][128]
            const int* __restrict__ row_start,       // [N+1]
            const unsigned short* __restrict__ Wn1t,
            const unsigned short* __restrict__ Wn2t,
            const float* __restrict__ bn1,
            const float* __restrict__ bn2,
            float* __restrict__ hout,
            int N)
{
  __shared__ unsigned short a_in[NBM * PE];
  __shared__ unsigned short t1[NBM * PT];
  const int tid = threadIdx.x, lane = tid & 63, wv = tid >> 6;
  const int l15 = lane & 15, lg = lane >> 4;

  bf16x8 fW1[2][8], fW2[2][4];
  float b1v[2], b2v[2];
#pragma unroll
  for (int nt = 0; nt < 2; ++nt) {
    int n = wv * 32 + nt * 16 + l15;
#pragma unroll
    for (int kt = 0; kt < 8; ++kt)
      fW1[nt][kt] = *(const bf16x8*)&Wn1t[n * 256 + kt * 32 + lg * 8];
#pragma unroll
    for (int kt = 0; kt < 4; ++kt)
      fW2[nt][kt] = *(const bf16x8*)&Wn2t[n * 128 + kt * 32 + lg * 8];
    b1v[nt] = bn1[n]; b2v[nt] = bn2[n];
  }

  const int ntiles = (N + NBM - 1) / NBM;
  for (int t = blockIdx.x; t < ntiles; t += gridDim.x) {
    const int base = t * NBM;
    // ---- stage h half: 256 threads x 32B = 8KB ----
    {
      int m = tid >> 3, part = tid & 7;
      int node = base + m; if (node >= N) node = N - 1;
      const uint4* src = (const uint4*)&hbf[(size_t)node * HDIM + part * 16];
      uint4 a = src[0], b = src[1];
      uint4* dst = (uint4*)&a_in[m * PE + part * 16];
      dst[0] = a; dst[1] = b;
    }
    // ---- agg half: 512 units = (m:32) x (cg:16, 8 cols); 2 units/thread.
    //      Per edge: one bf16x8 (16B) load/unit; 16 units/edge = 256B coalesced. ----
    {
      int unit = tid;
#pragma unroll
      for (int u = 0; u < 2; ++u, unit += 256) {
        int m = unit >> 4, cg = unit & 15;
        int node = base + m;
        float s[8] = {0.f, 0.f, 0.f, 0.f, 0.f, 0.f, 0.f, 0.f};
        if (node < N) {
          int er0 = row_start[node], er1 = row_start[node + 1];
#pragma unroll 4
          for (int e = er0; e < er1; ++e) {
            bf16x8 v = *(const bf16x8*)&ef[(size_t)e * HDIM + cg * 8];
#pragma unroll
            for (int j = 0; j < 8; ++j)
              s[j] += bf2f((unsigned short)v[j]);
          }
        }
        union { unsigned short us[8]; uint4 q; } p;
#pragma unroll
        for (int j = 0; j < 8; ++j) p.us[j] = f2bf(s[j]);
        *(uint4*)&a_in[m * PE + HDIM + cg * 8] = p.q;
      }
    }
    __syncthreads();

    f32x4 acc[2][2];
#pragma unroll
    for (int mt = 0; mt < 2; ++mt)
#pragma unroll
      for (int nt = 0; nt < 2; ++nt)
        acc[mt][nt] = (f32x4){0.f, 0.f, 0.f, 0.f};
#pragma unroll
    for (int kt = 0; kt < 8; ++kt) {
      bf16x8 a0 = *(const bf16x8*)&a_in[l15 * PE + kt * 32 + lg * 8];
      bf16x8 a1 = *(const bf16x8*)&a_in[(16 + l15) * PE + kt * 32 + lg * 8];
#pragma unroll
      for (int nt = 0; nt < 2; ++nt) {
        acc[0][nt] = mfma16(a0, fW1[nt][kt], acc[0][nt]);
        acc[1][nt] = mfma16(a1, fW1[nt][kt], acc[1][nt]);
      }
    }
#pragma unroll
    for (int mt = 0; mt < 2; ++mt)
#pragma unroll
      for (int nt = 0; nt < 2; ++nt) {
        int n = wv * 32 + nt * 16 + l15;
#pragma unroll
        for (int r = 0; r < 4; ++r) {
          int m = mt * 16 + lg * 4 + r;
          t1[m * PT + n] = f2bf(siluf(acc[mt][nt][r] + b1v[nt]));
        }
      }
    __syncthreads();

    f32x4 acc2[2][2];
#pragma unroll
    for (int mt = 0; mt < 2; ++mt)
#pragma unroll
      for (int nt = 0; nt < 2; ++nt)
        acc2[mt][nt] = (f32x4){0.f, 0.f, 0.f, 0.f};
#pragma unroll
    for (int kt = 0; kt < 4; ++kt) {
      bf16x8 a0 = *(const bf16x8*)&t1[l15 * PT + kt * 32 + lg * 8];
      bf16x8 a1 = *(const bf16x8*)&t1[(16 + l15) * PT + kt * 32 + lg * 8];
#pragma unroll
      for (int nt = 0; nt < 2; ++nt) {
        acc2[0][nt] = mfma16(a0, fW2[nt][kt], acc2[0][nt]);
        acc2[1][nt] = mfma16(a1, fW2[nt][kt], acc2[1][nt]);
      }
    }
#pragma unroll
    for (int mt = 0; mt < 2; ++mt)
#pragma unroll
      for (int nt = 0; nt < 2; ++nt) {
        int n = wv * 32 + nt * 16 + l15;
#pragma unroll
        for (int r = 0; r < 4; ++r) {
          int node = base + mt * 16 + lg * 4 + r;
          if (node < N)
            hout[(size_t)node * HDIM + n] = h[(size_t)node * HDIM + n] + acc2[mt][nt][r] + b2v[nt];
        }
      }
    __syncthreads();
  }
}

// ---------------- coord epilogue: CSR-contiguous trans sum ----------------
__global__ void k_coord(const float* __restrict__ coord,
                        const float* __restrict__ trans,   // [E][3]
                        const int* __restrict__ row_start,
                        float* __restrict__ out, int N) {
  int i = blockIdx.x * blockDim.x + threadIdx.x;
  if (i >= N * 3) return;
  int node = i / 3, axis = i - node * 3;
  int e0 = row_start[node], e1 = row_start[node + 1];
  float s = 0.f;
  for (int e = e0; e < e1; ++e) s += trans[(size_t)e * 3 + axis];
  float c = (float)(e1 - e0); if (c < 1.f) c = 1.f;
  out[i] = coord[i] + s / c;
}

extern "C" void kernel_launch(void* const* d_in, const int* in_sizes, int n_in,
                              void* d_out, int out_size, void* d_ws, size_t ws_size,
                              hipStream_t stream) {
  const float* h     = (const float*)d_in[0];
  const float* coord = (const float*)d_in[1];
  const int*   ei    = (const int*)d_in[2];
  const float* We1   = (const float*)d_in[3];
  const float* be1   = (const float*)d_in[4];
  const float* We2   = (const float*)d_in[5];
  const float* be2   = (const float*)d_in[6];
  const float* Wn1   = (const float*)d_in[7];
  const float* bn1   = (const float*)d_in[8];
  const float* Wn2   = (const float*)d_in[9];
  const float* bn2   = (const float*)d_in[10];
  const float* Wc1   = (const float*)d_in[11];
  const float* bc1   = (const float*)d_in[12];
  const float* Wc2   = (const float*)d_in[13];

  const int N = in_sizes[0] / HDIM;
  const int E = in_sizes[2] / 2;

  char* ws = (char*)d_ws;
  size_t off = 0;
  auto alloc = [&](size_t b) { void* p = ws + off; off = (off + b + 255) & ~(size_t)255; return p; };
  unsigned short* hbf  = (unsigned short*)alloc((size_t)N * HDIM * 2);
  unsigned short* We1t = (unsigned short*)alloc(256 * 128 * 2);
  unsigned short* We2t = (unsigned short*)alloc(128 * 128 * 2);
  unsigned short* Wc1t = (unsigned short*)alloc(128 * 128 * 2);
  unsigned short* Wn1t = (unsigned short*)alloc(256 * 128 * 2);
  unsigned short* Wn2t = (unsigned short*)alloc(128 * 128 * 2);
  int* deg       = (int*)alloc((size_t)N * 4);
  int* cursor    = (int*)alloc((size_t)N * 4);
  int* row_start = (int*)alloc(((size_t)N + 1) * 4);
  int* partial   = (int*)alloc(256 * 4);
  int* srow      = (int*)alloc((size_t)E * 4);
  int* scol      = (int*)alloc((size_t)E * 4);
  unsigned short* ef = (unsigned short*)alloc((size_t)E * HDIM * 2);  // 205 MB
  float* trans   = (float*)alloc((size_t)E * 3 * 4);                  // 9.6 MB

  hipMemsetAsync(deg, 0, (size_t)N * 4, stream);

  int n8 = N * HDIM / 8;
  k_cast_h<<<(n8 + 255) / 256, 256, 0, stream>>>(h, hbf, n8);
  k_transpose<<<(256 * 128 + 255) / 256, 256, 0, stream>>>(We1, We1t, 256, 128);
  k_transpose<<<(128 * 128 + 255) / 256, 256, 0, stream>>>(We2, We2t, 128, 128);
  k_transpose<<<(128 * 128 + 255) / 256, 256, 0, stream>>>(Wc1, Wc1t, 128, 128);
  k_transpose<<<(256 * 128 + 255) / 256, 256, 0, stream>>>(Wn1, Wn1t, 256, 128);
  k_transpose<<<(128 * 128 + 255) / 256, 256, 0, stream>>>(Wn2, Wn2t, 128, 128);

  // counting sort by row (parallel scan)
  int nb = (N + 255) / 256;   // <= 256
  k_hist<<<(E + 255) / 256, 256, 0, stream>>>(ei, deg, E);
  k_scan1<<<nb, 256, 0, stream>>>(deg, partial, N);
  k_scan2<<<1, 256, 0, stream>>>(partial, nb);
  k_scan3<<<nb, 256, 0, stream>>>(deg, partial, row_start, cursor, N, E);
  k_scatter<<<(E + 255) / 256, 256, 0, stream>>>(ei, cursor, srow, scol, E);

  k_edge<<<512, 512, 0, stream>>>(coord, srow, scol, hbf, We1t, We2t, Wc1t, We1,
                                  be1, be2, bc1, Wc2, ef, trans, E);

  float* hout = (float*)d_out;
  int node_tiles = (N + NBM - 1) / NBM;
  k_node<<<node_tiles, 256, 0, stream>>>(h, hbf, ef, row_start, Wn1t, Wn2t, bn1, bn2, hout, N);
  k_coord<<<(N * 3 + 255) / 256, 256, 0, stream>>>(coord, trans, row_start,
                                                   hout + (size_t)N * HDIM, N);
}

// Round 17
// 423.310 us; speedup vs baseline: 1.4597x; 1.1303x over previous
//
#include <hip/hip_runtime.h>

typedef short bf16x8 __attribute__((ext_vector_type(8)));
typedef float f32x4 __attribute__((ext_vector_type(4)));
typedef float f32x16 __attribute__((ext_vector_type(16)));

#define HDIM 128
#define BM 64    // edges per tile
#define PE 264   // e_in tile pitch (elems): 528B
#define PT 136   // mid tile pitch (elems): 272B

__device__ __forceinline__ unsigned short f2bf(float f) {
  union { float f; unsigned int u; } v; v.f = f;
  unsigned int r = v.u + 0x7fffu + ((v.u >> 16) & 1u);
  return (unsigned short)(r >> 16);
}
__device__ __forceinline__ float bf2f(unsigned short u) {
  union { unsigned int u; float f; } v; v.u = ((unsigned int)u) << 16; return v.f;
}
__device__ __forceinline__ float siluf(float x) {
  return x * __builtin_amdgcn_rcpf(1.f + __expf(-x));
}
__device__ __forceinline__ f32x4 mfma16(bf16x8 a, bf16x8 b, f32x4 c) {
  return __builtin_amdgcn_mfma_f32_16x16x32_bf16(a, b, c, 0, 0, 0);
}
__device__ __forceinline__ f32x16 mfma32(bf16x8 a, bf16x8 b, f32x16 c) {
  return __builtin_amdgcn_mfma_f32_32x32x16_bf16(a, b, c, 0, 0, 0);
}

// ---------------- prep ----------------
__global__ void k_cast_h(const float* __restrict__ h, unsigned short* __restrict__ hbf, int n8) {
  int i = blockIdx.x * blockDim.x + threadIdx.x;
  if (i >= n8) return;
  const float4* s = (const float4*)(h + (size_t)i * 8);
  float4 a = s[0], b = s[1];
  union { unsigned short us[8]; uint4 q; } p;
  p.us[0] = f2bf(a.x); p.us[1] = f2bf(a.y); p.us[2] = f2bf(a.z); p.us[3] = f2bf(a.w);
  p.us[4] = f2bf(b.x); p.us[5] = f2bf(b.y); p.us[6] = f2bf(b.z); p.us[7] = f2bf(b.w);
  ((uint4*)hbf)[i] = p.q;
}

// Wt[n*K + k] = bf16(W[k*Nn + n])
__global__ void k_transpose(const float* __restrict__ W, unsigned short* __restrict__ Wt, int K, int Nn) {
  int i = blockIdx.x * blockDim.x + threadIdx.x;
  if (i >= K * Nn) return;
  int k = i / Nn, n = i - k * Nn;
  Wt[n * K + k] = f2bf(W[i]);
}

// ---------------- counting sort by row ----------------
__global__ void k_hist(const int* __restrict__ ei, int* __restrict__ deg, int E) {
  int e = blockIdx.x * blockDim.x + threadIdx.x;
  if (e < E) atomicAdd(&deg[ei[e]], 1);
}

__global__ void k_scan1(const int* __restrict__ deg, int* __restrict__ partial, int N) {
  int i = blockIdx.x * 256 + threadIdx.x;
  int v = (i < N) ? deg[i] : 0;
#pragma unroll
  for (int m = 1; m < 64; m <<= 1) v += __shfl_xor(v, m);
  __shared__ int ws[4];
  if ((threadIdx.x & 63) == 0) ws[threadIdx.x >> 6] = v;
  __syncthreads();
  if (threadIdx.x == 0) partial[blockIdx.x] = ws[0] + ws[1] + ws[2] + ws[3];
}

__global__ void k_scan2(int* __restrict__ partial, int nb) {
  __shared__ int arr[256];
  int t = threadIdx.x;
  int self = (t < nb) ? partial[t] : 0;
  arr[t] = self;
  __syncthreads();
  for (int o = 1; o < 256; o <<= 1) {
    int u = (t >= o) ? arr[t - o] : 0;
    __syncthreads();
    arr[t] += u;
    __syncthreads();
  }
  if (t < nb) partial[t] = arr[t] - self;   // exclusive
}

__global__ void k_scan3(const int* __restrict__ deg, const int* __restrict__ partial,
                        int* __restrict__ row_start, int* __restrict__ cursor, int N, int E) {
  __shared__ int arr[256];
  int b = blockIdx.x, t = threadIdx.x, i = b * 256 + t;
  int v = (i < N) ? deg[i] : 0;
  arr[t] = v;
  __syncthreads();
  for (int o = 1; o < 256; o <<= 1) {
    int u = (t >= o) ? arr[t - o] : 0;
    __syncthreads();
    arr[t] += u;
    __syncthreads();
  }
  if (i < N) {
    int ex = partial[b] + arr[t] - v;
    row_start[i] = ex; cursor[i] = ex;
  }
  if (b == 0 && t == 0) row_start[N] = E;
}

__global__ void k_scatter(const int* __restrict__ ei, int* __restrict__ cursor,
                          int* __restrict__ srow, int* __restrict__ scol, int E) {
  int e = blockIdx.x * blockDim.x + threadIdx.x;
  if (e < E) {
    int r = ei[e];
    int pos = atomicAdd(&cursor[r], 1);
    srow[pos] = r;
    scol[pos] = ei[E + e];
  }
}

// ---------------- edge kernel: sorted edges, BM=64, 4 waves x 32 cols,
//                  32x32x16 MFMA (halves LDS A-read count vs 8x16-col),
//                  XCD-chunked, zero atomics, streams ef + trans.
// (256,2): VGPR cap 256 >> ~200 needed (128 weight VGPRs) -> no spill. -------
__global__ __launch_bounds__(256, 2)
void k_edge(const float* __restrict__ coord,
            const int* __restrict__ srow,
            const int* __restrict__ scol,
            const unsigned short* __restrict__ hbf,
            const unsigned short* __restrict__ We1t,
            const unsigned short* __restrict__ We2t,
            const unsigned short* __restrict__ Wc1t,
            const float* __restrict__ We1,   // [257][128], row 256 = radial row
            const float* __restrict__ be1,
            const float* __restrict__ be2,
            const float* __restrict__ bc1,
            const float* __restrict__ Wc2,   // [128]
            unsigned short* __restrict__ ef,   // [E][128] bf16 out
            float* __restrict__ trans,         // [E][3] f32 out
            int E)
{
  __shared__ unsigned short e_in[BM * PE];   // also hosts ef_t (disjoint in time)
  __shared__ unsigned short m_t[BM * PT];    // L1 output, then L3 w-terms
  __shared__ float cd_lds[BM][3];
  __shared__ float rad_lds[BM];
  unsigned short* ef_t = e_in;   // layer-2 output; e_in reads end before B2

  const int tid = threadIdx.x;
  const int lane = tid & 63;
  const int wv = tid >> 6;       // wave 0..3, owns cols [wv*32, wv*32+32)
  const int l31 = lane & 31;
  const int hi = lane >> 5;      // 0..1 (k-slot half)
  const int col = wv * 32 + l31;

  // ---- weight B-fragments in registers (per wave: its 32 cols) ----
  // frag[kt]: lane holds W[kt*16 + hi*8 + j][col], j=0..7
  bf16x8 fW1[16], fW2[8], fW3[8];
#pragma unroll
  for (int kt = 0; kt < 16; ++kt)
    fW1[kt] = *(const bf16x8*)&We1t[col * 256 + kt * 16 + hi * 8];
#pragma unroll
  for (int kt = 0; kt < 8; ++kt) {
    fW2[kt] = *(const bf16x8*)&We2t[col * 128 + kt * 16 + hi * 8];
    fW3[kt] = *(const bf16x8*)&Wc1t[col * 128 + kt * 16 + hi * 8];
  }
  const float bias1 = be1[col], bias2 = be2[col], bias3 = bc1[col];
  const float wc2v = Wc2[col];
  const float w256 = We1[256 * 128 + col];

  // ---- XCD-chunked contiguous tile range ----
  const int ntiles = (E + BM - 1) / BM;
  const int nblk = gridDim.x;                 // multiple of 8
  const int vbid = (blockIdx.x & 7) * (nblk >> 3) + (blockIdx.x >> 3);
  const int tpb = (ntiles + nblk - 1) / nblk;
  int lo = vbid * tpb, hi2 = lo + tpb; if (hi2 > ntiles) hi2 = ntiles;

  const int gm = tid >> 2;                   // edge-in-tile 0..63
  const int gq = tid & 3;
  const int ghalf = gq >> 1, gpart = gq & 1; // node half, 128B part
  const int cm = tid >> 2, cq = tid & 3;     // ef copy: row, 64B part

  for (int t = lo; t < hi2; ++t) {
    const int e0 = t * BM;

    // ---- stage: geometry (64 threads) + gather h rows (all 256) ----
    if (tid < BM) {
      int e = e0 + tid;
      float dx = 0.f, dy = 0.f, dz = 0.f;
      if (e < E) {
        int r = srow[e], c = scol[e];
        dx = coord[r * 3 + 0] - coord[c * 3 + 0];
        dy = coord[r * 3 + 1] - coord[c * 3 + 1];
        dz = coord[r * 3 + 2] - coord[c * 3 + 2];
      }
      cd_lds[tid][0] = dx; cd_lds[tid][1] = dy; cd_lds[tid][2] = dz;
      rad_lds[tid] = dx * dx + dy * dy + dz * dz;
    }
    {
      // 256 threads x 128B = 32KB = 64 edges x 2 nodes x 128 shorts
      int e = e0 + gm;
      int node = 0;
      if (e < E) node = ghalf ? scol[e] : srow[e];
      const uint4* src = (const uint4*)&hbf[(size_t)node * HDIM + gpart * 64];
      uint4 a0 = src[0], a1 = src[1], a2 = src[2], a3 = src[3];
      uint4 a4 = src[4], a5 = src[5], a6 = src[6], a7 = src[7];
      uint4* dst = (uint4*)&e_in[gm * PE + ghalf * HDIM + gpart * 64];
      dst[0] = a0; dst[1] = a1; dst[2] = a2; dst[3] = a3;
      dst[4] = a4; dst[5] = a5; dst[6] = a6; dst[7] = a7;
    }
    __syncthreads();   // B1

    // ---- layer 1: [64 x 256] @ We1[256 x 128] (32x32x16) ----
    f32x16 acc[2];
#pragma unroll
    for (int mt = 0; mt < 2; ++mt)
#pragma unroll
      for (int r = 0; r < 16; ++r) acc[mt][r] = 0.f;
#pragma unroll
    for (int kt = 0; kt < 16; ++kt) {
#pragma unroll
      for (int mt = 0; mt < 2; ++mt) {
        bf16x8 a = *(const bf16x8*)&e_in[(mt * 32 + l31) * PE + kt * 16 + hi * 8];
        acc[mt] = mfma32(a, fW1[kt], acc[mt]);
      }
    }
#pragma unroll
    for (int mt = 0; mt < 2; ++mt)
#pragma unroll
      for (int r = 0; r < 16; ++r) {
        int m = mt * 32 + (r & 3) + 8 * (r >> 2) + 4 * hi;
        float x = acc[mt][r] + bias1 + rad_lds[m] * w256;
        m_t[m * PT + col] = f2bf(siluf(x));
      }
    __syncthreads();   // B2 (e_in reads done; ef_t may overwrite)

    // ---- layer 2: m @ We2 -> edge_feat ----
#pragma unroll
    for (int mt = 0; mt < 2; ++mt)
#pragma unroll
      for (int r = 0; r < 16; ++r) acc[mt][r] = 0.f;
#pragma unroll
    for (int kt = 0; kt < 8; ++kt) {
#pragma unroll
      for (int mt = 0; mt < 2; ++mt) {
        bf16x8 a = *(const bf16x8*)&m_t[(mt * 32 + l31) * PT + kt * 16 + hi * 8];
        acc[mt] = mfma32(a, fW2[kt], acc[mt]);
      }
    }
#pragma unroll
    for (int mt = 0; mt < 2; ++mt)
#pragma unroll
      for (int r = 0; r < 16; ++r) {
        int m = mt * 32 + (r & 3) + 8 * (r >> 2) + 4 * hi;
        ef_t[m * PT + col] = f2bf(siluf(acc[mt][r] + bias2));
      }
    __syncthreads();   // B3 (m_t reads done; m_t reusable for w-terms)

    // ---- stream ef tile to global (coalesced, plain stores) ----
    if (e0 + cm < E) {
      int base = cq * 32;
      uint4 a0 = *(const uint4*)&ef_t[cm * PT + base + 0];
      uint4 a1 = *(const uint4*)&ef_t[cm * PT + base + 8];
      uint4 a2 = *(const uint4*)&ef_t[cm * PT + base + 16];
      uint4 a3 = *(const uint4*)&ef_t[cm * PT + base + 24];
      uint4* dst = (uint4*)&ef[(size_t)(e0 + cm) * HDIM + base];
      dst[0] = a0; dst[1] = a1; dst[2] = a2; dst[3] = a3;
    }

    // ---- layer 3: edge_feat @ Wc1 -> silu -> *Wc2 -> w-terms into m_t ----
#pragma unroll
    for (int mt = 0; mt < 2; ++mt)
#pragma unroll
      for (int r = 0; r < 16; ++r) acc[mt][r] = 0.f;
#pragma unroll
    for (int kt = 0; kt < 8; ++kt) {
#pragma unroll
      for (int mt = 0; mt < 2; ++mt) {
        bf16x8 a = *(const bf16x8*)&ef_t[(mt * 32 + l31) * PT + kt * 16 + hi * 8];
        acc[mt] = mfma32(a, fW3[kt], acc[mt]);
      }
    }
#pragma unroll
    for (int mt = 0; mt < 2; ++mt)
#pragma unroll
      for (int r = 0; r < 16; ++r) {
        int m = mt * 32 + (r & 3) + 8 * (r >> 2) + 4 * hi;
        m_t[m * PT + col] = f2bf(siluf(acc[mt][r] + bias3) * wc2v);
      }
    __syncthreads();   // B4 (w-terms complete)

    // ---- trans: one thread per edge sums 128 w-terms (16 x b128), stores 3 ----
    if (tid < BM) {
      int e = e0 + tid;
      if (e < E) {
        float w = 0.f;
#pragma unroll
        for (int c8 = 0; c8 < 16; ++c8) {
          bf16x8 v = *(const bf16x8*)&m_t[tid * PT + c8 * 8];
#pragma unroll
          for (int j = 0; j < 8; ++j) w += bf2f((unsigned short)v[j]);
        }
        trans[(size_t)e * 3 + 0] = cd_lds[tid][0] * w;
        trans[(size_t)e * 3 + 1] = cd_lds[tid][1] * w;
        trans[(size_t)e * 3 + 2] = cd_lds[tid][2] * w;
      }
    }
    __syncthreads();   // B5 (protect LDS for next tile)
  }
}

// ---------------- node kernel: CSR-contiguous agg (vectorized) + node MLP ----
#define NBM 32
__global__ __launch_bounds__(256, 3)
void k_node(const float* __restrict__ h,
            const unsigned short* __restrict__ hbf,
            const unsigned short* __restrict__ ef,   // [E][128]
            const int* __restrict__ row_start,       // [N+1]
            const unsigned short* __restrict__ Wn1t,
            const unsigned short* __restrict__ Wn2t,
            const float* __restrict__ bn1,
            const float* __restrict__ bn2,
            float* __restrict__ hout,
            int N)
{
  __shared__ unsigned short a_in[NBM * PE];
  __shared__ unsigned short t1[NBM * PT];
  const int tid = threadIdx.x, lane = tid & 63, wv = tid >> 6;
  const int l15 = lane & 15, lg = lane >> 4;

  bf16x8 fW1[2][8], fW2[2][4];
  float b1v[2], b2v[2];
#pragma unroll
  for (int nt = 0; nt < 2; ++nt) {
    int n = wv * 32 + nt * 16 + l15;
#pragma unroll
    for (int kt = 0; kt < 8; ++kt)
      fW1[nt][kt] = *(const bf16x8*)&Wn1t[n * 256 + kt * 32 + lg * 8];
#pragma unroll
    for (int kt = 0; kt < 4; ++kt)
      fW2[nt][kt] = *(const bf16x8*)&Wn2t[n * 128 + kt * 32 + lg * 8];
    b1v[nt] = bn1[n]; b2v[nt] = bn2[n];
  }

  const int ntiles = (N + NBM - 1) / NBM;
  for (int t = blockIdx.x; t < ntiles; t += gridDim.x) {
    const int base = t * NBM;
    {
      int m = tid >> 3, part = tid & 7;
      int node = base + m; if (node >= N) node = N - 1;
      const uint4* src = (const uint4*)&hbf[(size_t)node * HDIM + part * 16];
      uint4 a = src[0], b = src[1];
      uint4* dst = (uint4*)&a_in[m * PE + part * 16];
      dst[0] = a; dst[1] = b;
    }
    {
      int unit = tid;
#pragma unroll
      for (int u = 0; u < 2; ++u, unit += 256) {
        int m = unit >> 4, cg = unit & 15;
        int node = base + m;
        float s[8] = {0.f, 0.f, 0.f, 0.f, 0.f, 0.f, 0.f, 0.f};
        if (node < N) {
          int er0 = row_start[node], er1 = row_start[node + 1];
#pragma unroll 4
          for (int e = er0; e < er1; ++e) {
            bf16x8 v = *(const bf16x8*)&ef[(size_t)e * HDIM + cg * 8];
#pragma unroll
            for (int j = 0; j < 8; ++j)
              s[j] += bf2f((unsigned short)v[j]);
          }
        }
        union { unsigned short us[8]; uint4 q; } p;
#pragma unroll
        for (int j = 0; j < 8; ++j) p.us[j] = f2bf(s[j]);
        *(uint4*)&a_in[m * PE + HDIM + cg * 8] = p.q;
      }
    }
    __syncthreads();

    f32x4 acc[2][2];
#pragma unroll
    for (int mt = 0; mt < 2; ++mt)
#pragma unroll
      for (int nt = 0; nt < 2; ++nt)
        acc[mt][nt] = (f32x4){0.f, 0.f, 0.f, 0.f};
#pragma unroll
    for (int kt = 0; kt < 8; ++kt) {
      bf16x8 a0 = *(const bf16x8*)&a_in[l15 * PE + kt * 32 + lg * 8];
      bf16x8 a1 = *(const bf16x8*)&a_in[(16 + l15) * PE + kt * 32 + lg * 8];
#pragma unroll
      for (int nt = 0; nt < 2; ++nt) {
        acc[0][nt] = mfma16(a0, fW1[nt][kt], acc[0][nt]);
        acc[1][nt] = mfma16(a1, fW1[nt][kt], acc[1][nt]);
      }
    }
#pragma unroll
    for (int mt = 0; mt < 2; ++mt)
#pragma unroll
      for (int nt = 0; nt < 2; ++nt) {
        int n = wv * 32 + nt * 16 + l15;
#pragma unroll
        for (int r = 0; r < 4; ++r) {
          int m = mt * 16 + lg * 4 + r;
          t1[m * PT + n] = f2bf(siluf(acc[mt][nt][r] + b1v[nt]));
        }
      }
    __syncthreads();

    f32x4 acc2[2][2];
#pragma unroll
    for (int mt = 0; mt < 2; ++mt)
#pragma unroll
      for (int nt = 0; nt < 2; ++nt)
        acc2[mt][nt] = (f32x4){0.f, 0.f, 0.f, 0.f};
#pragma unroll
    for (int kt = 0; kt < 4; ++kt) {
      bf16x8 a0 = *(const bf16x8*)&t1[l15 * PT + kt * 32 + lg * 8];
      bf16x8 a1 = *(const bf16x8*)&t1[(16 + l15) * PT + kt * 32 + lg * 8];
#pragma unroll
      for (int nt = 0; nt < 2; ++nt) {
        acc2[0][nt] = mfma16(a0, fW2[nt][kt], acc2[0][nt]);
        acc2[1][nt] = mfma16(a1, fW2[nt][kt], acc2[1][nt]);
      }
    }
#pragma unroll
    for (int mt = 0; mt < 2; ++mt)
#pragma unroll
      for (int nt = 0; nt < 2; ++nt) {
        int n = wv * 32 + nt * 16 + l15;
#pragma unroll
        for (int r = 0; r < 4; ++r) {
          int node = base + mt * 16 + lg * 4 + r;
          if (node < N)
            hout[(size_t)node * HDIM + n] = h[(size_t)node * HDIM + n] + acc2[mt][nt][r] + b2v[nt];
        }
      }
    __syncthreads();
  }
}

// ---------------- coord epilogue: CSR-contiguous trans sum ----------------
__global__ void k_coord(const float* __restrict__ coord,
                        const float* __restrict__ trans,   // [E][3]
                        const int* __restrict__ row_start,
                        float* __restrict__ out, int N) {
  int i = blockIdx.x * blockDim.x + threadIdx.x;
  if (i >= N * 3) return;
  int node = i / 3, axis = i - node * 3;
  int e0 = row_start[node], e1 = row_start[node + 1];
  float s = 0.f;
  for (int e = e0; e < e1; ++e) s += trans[(size_t)e * 3 + axis];
  float c = (float)(e1 - e0); if (c < 1.f) c = 1.f;
  out[i] = coord[i] + s / c;
}

extern "C" void kernel_launch(void* const* d_in, const int* in_sizes, int n_in,
                              void* d_out, int out_size, void* d_ws, size_t ws_size,
                              hipStream_t stream) {
  const float* h     = (const float*)d_in[0];
  const float* coord = (const float*)d_in[1];
  const int*   ei    = (const int*)d_in[2];
  const float* We1   = (const float*)d_in[3];
  const float* be1   = (const float*)d_in[4];
  const float* We2   = (const float*)d_in[5];
  const float* be2   = (const float*)d_in[6];
  const float* Wn1   = (const float*)d_in[7];
  const float* bn1   = (const float*)d_in[8];
  const float* Wn2   = (const float*)d_in[9];
  const float* bn2   = (const float*)d_in[10];
  const float* Wc1   = (const float*)d_in[11];
  const float* bc1   = (const float*)d_in[12];
  const float* Wc2   = (const float*)d_in[13];

  const int N = in_sizes[0] / HDIM;
  const int E = in_sizes[2] / 2;

  char* ws = (char*)d_ws;
  size_t off = 0;
  auto alloc = [&](size_t b) { void* p = ws + off; off = (off + b + 255) & ~(size_t)255; return p; };
  unsigned short* hbf  = (unsigned short*)alloc((size_t)N * HDIM * 2);
  unsigned short* We1t = (unsigned short*)alloc(256 * 128 * 2);
  unsigned short* We2t = (unsigned short*)alloc(128 * 128 * 2);
  unsigned short* Wc1t = (unsigned short*)alloc(128 * 128 * 2);
  unsigned short* Wn1t = (unsigned short*)alloc(256 * 128 * 2);
  unsigned short* Wn2t = (unsigned short*)alloc(128 * 128 * 2);
  int* deg       = (int*)alloc((size_t)N * 4);
  int* cursor    = (int*)alloc((size_t)N * 4);
  int* row_start = (int*)alloc(((size_t)N + 1) * 4);
  int* partial   = (int*)alloc(256 * 4);
  int* srow      = (int*)alloc((size_t)E * 4);
  int* scol      = (int*)alloc((size_t)E * 4);
  unsigned short* ef = (unsigned short*)alloc((size_t)E * HDIM * 2);  // 205 MB
  float* trans   = (float*)alloc((size_t)E * 3 * 4);                  // 9.6 MB

  hipMemsetAsync(deg, 0, (size_t)N * 4, stream);

  int n8 = N * HDIM / 8;
  k_cast_h<<<(n8 + 255) / 256, 256, 0, stream>>>(h, hbf, n8);
  k_transpose<<<(256 * 128 + 255) / 256, 256, 0, stream>>>(We1, We1t, 256, 128);
  k_transpose<<<(128 * 128 + 255) / 256, 256, 0, stream>>>(We2, We2t, 128, 128);
  k_transpose<<<(128 * 128 + 255) / 256, 256, 0, stream>>>(Wc1, Wc1t, 128, 128);
  k_transpose<<<(256 * 128 + 255) / 256, 256, 0, stream>>>(Wn1, Wn1t, 256, 128);
  k_transpose<<<(128 * 128 + 255) / 256, 256, 0, stream>>>(Wn2, Wn2t, 128, 128);

  // counting sort by row (parallel scan)
  int nb = (N + 255) / 256;   // <= 256
  k_hist<<<(E + 255) / 256, 256, 0, stream>>>(ei, deg, E);
  k_scan1<<<nb, 256, 0, stream>>>(deg, partial, N);
  k_scan2<<<1, 256, 0, stream>>>(partial, nb);
  k_scan3<<<nb, 256, 0, stream>>>(deg, partial, row_start, cursor, N, E);
  k_scatter<<<(E + 255) / 256, 256, 0, stream>>>(ei, cursor, srow, scol, E);

  k_edge<<<512, 256, 0, stream>>>(coord, srow, scol, hbf, We1t, We2t, Wc1t, We1,
                                  be1, be2, bc1, Wc2, ef, trans, E);

  float* hout = (float*)d_out;
  int node_tiles = (N + NBM - 1) / NBM;
  k_node<<<node_tiles, 256, 0, stream>>>(h, hbf, ef, row_start, Wn1t, Wn2t, bn1, bn2, hout, N);
  k_coord<<<(N * 3 + 255) / 256, 256, 0, stream>>>(coord, trans, row_start,
                                                   hout + (size_t)N * HDIM, N);
}